// Round 7
// baseline (694.524 us; speedup 1.0000x reference)
//
#include <hip/hip_runtime.h>
#include <math.h>

#define S 4096
#define N_NODES 2048
#define N_CHILD 4096
#define NNZ 32768
#define TSM 512    // samples per main unit
#define TN 8       // nodes per main unit
#define CAP 96     // padded-row capacity
#define LP 516     // lds row pitch (floats) in main phase

typedef float f32x2 __attribute__((ext_vector_type(2)));

// R6 post-mortem: six prep structures all 58-67us; total flat 221-227 even
// when prep's dispatch moved 8us. Dispatch_Id deltas all multiples of 14 ->
// ~11 harness restore dispatches + ours per iteration; dispatch-sum ~112us
// vs dur_us ~225. Lever = dispatch count/span, not kernel internals.
// R7: single fused persistent kernel. 2048 blocks x 256 thr, LB(256,8) =
// exact full residency (32 waves/CU, 16.5KiB LDS, VGPR<=64) -> spin-sync is
// deadlock-free. Slice-local dependency: main(slice k) waits on texp(slice k)
// + scatter via device-scope release/acquire counters (G16).

static __device__ inline void fma16(uint4 x, f32x2 w2, f32x2* a2) {
#pragma unroll
    for (int q = 0; q < 4; ++q) {
        unsigned int word = (q == 0) ? x.x : (q == 1) ? x.y : (q == 2) ? x.z : x.w;
        f32x2 lo = __builtin_amdgcn_cvt_pk_f32_fp8(word, false);
        f32x2 hi = __builtin_amdgcn_cvt_pk_f32_fp8(word, true);
        a2[q * 2 + 0] = lo * w2 + a2[q * 2 + 0];   // v_pk_fma_f32
        a2[q * 2 + 1] = hi * w2 + a2[q * 2 + 1];
    }
}

__global__ __launch_bounds__(256, 8) void fused_kernel(
        const float* __restrict__ ll0, const float* __restrict__ ll1,
        const float* __restrict__ w0d, const float* __restrict__ w1d,
        const int* __restrict__ w0r, const int* __restrict__ w0c,
        const int* __restrict__ w1r, const int* __restrict__ w1c,
        unsigned char* __restrict__ ET, int2* __restrict__ ent,
        int* __restrict__ counts, int* __restrict__ sync_,
        float* __restrict__ out) {
    __shared__ float smem[TN * LP];               // 16512 B (phase-shared)
    unsigned int* tile = (unsigned int*)smem;     // texp view (5120 B used)
    int t = threadIdx.x, b = blockIdx.x;
    int wave = t >> 6, lane = t & 63;
    int sigma = b >> 8;                           // texp slice of this block

    // ---- phase 0: scatter (blocks 1792..2047, 1 entry/thread) ----
    if (sigma == 7) {
        int k = (b - 1792) * 256 + t;
        int row, col; float w;
        if (k < NNZ) { row = w0r[k]; col = w0c[k]; w = w0d[k]; }
        else { int kk = k - NNZ; row = w1r[kk]; col = w1c[kk] + N_CHILD; w = w1d[kk]; }
        int pos = atomicAdd(&counts[row], 1);
        if (pos < CAP)
            ent[row * CAP + pos] = make_int2(col, __float_as_int(__expf(w)));
        __syncthreads();                          // drain stores (vmcnt 0)
        if (t == 0) {
            __threadfence();
            __hip_atomic_fetch_add(&sync_[0], 1, __ATOMIC_RELEASE,
                                   __HIP_MEMORY_SCOPE_AGENT);
        }
    }

    // ---- phase 1: texp, 4 units of 16 samples x 256 cols, one slice ----
    // ET[(z*N_CHILD + c)*S + s] = fp8_e4m3(exp(ll_z[s, c]))
    int r = b & 255;
    int z = r & 1, ct = (r >> 1) & 15, sgroup = r >> 5;
    int c0 = ct * 256;
    const float* ll = z ? ll1 : ll0;
    for (int j = 0; j < 4; ++j) {                 // 64 samples: sector-complete
        int s0 = sigma * 512 + sgroup * 64 + j * 16;
        const float* p = ll + (size_t)(s0 + wave * 4) * N_CHILD + c0 + lane * 4;
        float4 a0 = *(const float4*)(p);
        float4 a1 = *(const float4*)(p + N_CHILD);
        float4 a2 = *(const float4*)(p + 2 * N_CHILD);
        float4 a3 = *(const float4*)(p + 3 * N_CHILD);
#pragma unroll
        for (int k = 0; k < 4; ++k) {
            float e0 = __expf(((const float*)&a0)[k]);
            float e1 = __expf(((const float*)&a1)[k]);
            float e2 = __expf(((const float*)&a2)[k]);
            float e3 = __expf(((const float*)&a3)[k]);
            unsigned int wlo = (unsigned int)__builtin_amdgcn_cvt_pk_fp8_f32(
                e0, e1, 0, false);
            unsigned int wfull = (unsigned int)__builtin_amdgcn_cvt_pk_fp8_f32(
                e2, e3, (int)wlo, true);
            // storage row f(c)=(c&3)*64+(c>>2)=k*64+lane; bank stride 5: free
            tile[(k * 64 + lane) * 5 + wave] = wfull;
        }
        __syncthreads();
        unsigned int d0 = tile[t * 5 + 0];        // conflict-free (stride 5)
        unsigned int d1 = tile[t * 5 + 1];
        unsigned int d2 = tile[t * 5 + 2];
        unsigned int d3 = tile[t * 5 + 3];
        int c = (t & 63) * 4 + (t >> 6);
        unsigned char* dst = ET + (size_t)(z * N_CHILD + c0 + c) * S + s0;
        *(uint4*)dst = make_uint4(d0, d1, d2, d3);
        __syncthreads();                          // WAR before next j
    }
    if (t == 0) {
        __threadfence();
        __hip_atomic_fetch_add(&sync_[1 + sigma], 1, __ATOMIC_RELEASE,
                               __HIP_MEMORY_SCOPE_AGENT);
    }

    // ---- phase 2: main, unit = b: out[s,i]=log(sum ET*ew)-log(sum ew) ----
    int s_m = b & 7, nb = b >> 3, i0 = nb * TN;
    if (t == 0) {
        while (__hip_atomic_load(&sync_[0], __ATOMIC_ACQUIRE,
                                 __HIP_MEMORY_SCOPE_AGENT) < 256)
            __builtin_amdgcn_s_sleep(2);
        while (__hip_atomic_load(&sync_[1 + s_m], __ATOMIC_ACQUIRE,
                                 __HIP_MEMORY_SCOPE_AGENT) < 256)
            __builtin_amdgcn_s_sleep(2);
    }
    __syncthreads();
    int hs = lane >> 5, sl = lane & 31;
    const unsigned char* ETs = ET + s_m * TSM + sl * 16;
    for (int jj = 0; jj < 2; ++jj) {
        int j = wave * 2 + jj;
        int i = i0 + j;
        int cnt = __builtin_amdgcn_readfirstlane(counts[i]);
        if (cnt > CAP) cnt = CAP;
        const int2* eb = ent + i * CAP;
        f32x2 a2[8];
#pragma unroll
        for (int u = 0; u < 8; ++u) a2[u] = (f32x2){0.f, 0.f};
        float zz = 0.f;
        int n = (cnt + 1 - hs) >> 1;
        int t2 = 0;
        for (; t2 + 1 < n; t2 += 2) {
            int2 e0 = eb[hs + 2 * t2];
            int2 e1 = eb[hs + 2 * t2 + 2];
            uint4 x0 = *(const uint4*)(ETs + (size_t)e0.x * S);
            uint4 x1 = *(const uint4*)(ETs + (size_t)e1.x * S);
            float w0 = __uint_as_float(e0.y);
            float w1 = __uint_as_float(e1.y);
            f32x2 w02 = {w0, w0};
            f32x2 w12 = {w1, w1};
            fma16(x0, w02, a2);
            fma16(x1, w12, a2);
            zz += w0 + w1;
        }
        if (t2 < n) {
            int2 e0 = eb[hs + 2 * t2];
            uint4 x0 = *(const uint4*)(ETs + (size_t)e0.x * S);
            float w0 = __uint_as_float(e0.y);
            f32x2 w02 = {w0, w0};
            fma16(x0, w02, a2);
            zz += w0;
        }
        float fl[16];
#pragma unroll
        for (int u = 0; u < 8; ++u) { fl[2 * u] = a2[u].x; fl[2 * u + 1] = a2[u].y; }
#pragma unroll
        for (int u = 0; u < 16; ++u) fl[u] += __shfl_xor(fl[u], 32);
        zz += __shfl_xor(zz, 32);
        float lz = __logf(zz);
        float rr[8];
#pragma unroll
        for (int u = 0; u < 8; ++u) {
            float sel = hs ? fl[8 + u] : fl[u];
            rr[u] = __logf(sel) - lz;
        }
        float* dstl = &smem[j * LP + sl * 16 + hs * 8];
        *(float4*)(dstl)     = make_float4(rr[0], rr[1], rr[2], rr[3]);
        *(float4*)(dstl + 4) = make_float4(rr[4], rr[5], rr[6], rr[7]);
    }
    __syncthreads();
    float* obase = out + (size_t)s_m * TSM * N_NODES + i0;
#pragma unroll
    for (int q = 0; q < 8; ++q) {
        int elem = (t + 256 * q) * 2;
        int s_l = elem >> 3;
        int i_l = elem & 7;
        float2 v;
        v.x = smem[i_l * LP + s_l];
        v.y = smem[(i_l + 1) * LP + s_l];
        *(float2*)&obase[(size_t)s_l * N_NODES + i_l] = v;
    }
}

// ---- launch ---------------------------------------------------------------

extern "C" void kernel_launch(void* const* d_in, const int* in_sizes, int n_in,
                              void* d_out, int out_size, void* d_ws, size_t ws_size,
                              hipStream_t stream) {
    const float* ll0 = (const float*)d_in[0];
    const float* ll1 = (const float*)d_in[1];
    const float* w0d = (const float*)d_in[2];
    const float* w1d = (const float*)d_in[3];
    const int*   w0r = (const int*)d_in[4];
    const int*   w0c = (const int*)d_in[5];
    const int*   w1r = (const int*)d_in[6];
    const int*   w1c = (const int*)d_in[7];
    float* out = (float*)d_out;

    unsigned char* ET = (unsigned char*)d_ws;                    // 32 MiB
    int2* ent   = (int2*)(ET + (size_t)2 * N_CHILD * S);         // 1.5 MiB
    int*  counts = (int*)(ent + (size_t)N_NODES * CAP);          // 8 KiB
    int*  sync_  = counts + N_NODES;                             // 16 ints

    hipMemsetAsync(counts, 0, sizeof(int) * (N_NODES + 16), stream);
    fused_kernel<<<2048, 256, 0, stream>>>(ll0, ll1, w0d, w1d, w0r, w0c,
                                           w1r, w1c, ET, ent, counts, sync_, out);
}

// Round 8
// 218.996 us; speedup vs baseline: 3.1714x; 3.1714x over previous
//
#include <hip/hip_runtime.h>
#include <math.h>

#define S 4096
#define N_NODES 2048
#define N_CHILD 4096
#define NNZ 32768
#define NNZ_TOTAL (2 * NNZ)
#define TSM 512    // samples per main block
#define TN 8       // nodes per main block
#define CAP 96     // padded-row capacity (mean 32, sigma 5.7 -> 96 is +11 sigma)
#define LP 516     // lds row pitch (floats) in main

typedef float f32x2 __attribute__((ext_vector_type(2)));

// ---- prep: blocks 0..63 scatter entries to padded rows; 64..2111 exp+transpose
// ET layout: ET[(m*N_CHILD + c)*S + s] = fp8_e4m3(exp(ll_m[s, c]))
// texp block bits (bt = b-64): [0:2]=slice (XCD pin), [3]=sthalf, [4:9]=ct, [10]=z
//
// Session ledger (R1-R7): six prep structures (scalar/dwordx4 loads, 256/1024
// thr, 256B/1KiB contiguity, sector-complete stores, pk-fma main) all land
// 221-227us total; fused persistent kernel with device-scope sync = 694us
// (L2 writeback/invalidate storm: WRITE 37->180MB, FETCH 66->119MB).
// Dispatch-sum ~112us + ~110us harness-fixed (14 dispatches/iter). Kernel HBM
// bytes (~170MB) are near the workload floor at the delivered ~1.7-2 TB/s.
// This file = R1 optimum, byte-identical revert.

__global__ __launch_bounds__(1024, 8) void prep_kernel(
        const float* __restrict__ ll0, const float* __restrict__ ll1,
        const float* __restrict__ w0d, const float* __restrict__ w1d,
        const int* __restrict__ w0r, const int* __restrict__ w0c,
        const int* __restrict__ w1r, const int* __restrict__ w1c,
        unsigned char* __restrict__ ET, int2* __restrict__ ent,
        int* __restrict__ counts) {
    __shared__ unsigned short tile[64 * 130];   // 16640 B
    int t = threadIdx.x;
    int b = blockIdx.x;
    if (b < 64) {
        // ---- scatter: fully parallel, no scan needed (padded rows) ----
        int k = b * 1024 + t;
        int row, col; float w;
        if (k < NNZ) { row = w0r[k]; col = w0c[k]; w = w0d[k]; }
        else { int kk = k - NNZ; row = w1r[kk]; col = w1c[kk] + N_CHILD; w = w1d[kk]; }
        int pos = atomicAdd(&counts[row], 1);
        if (pos < CAP)
            ent[row * CAP + pos] = make_int2(col, __float_as_int(__expf(w)));
        return;
    }
    // ---- exp + transpose tile: 64 cols x 256 samples ----
    int bt = b - 64;
    int slice = bt & 7;
    int sthalf = (bt >> 3) & 1;
    int ct = (bt >> 4) & 63;
    int z = (bt >> 10) & 1;
    int c0 = ct * 64;
    int s0 = slice * 512 + sthalf * 256;
    const float* ll = z ? ll1 : ll0;
    int wave = t >> 6, lane = t & 63;
    // preload ALL 16 values -> 16 loads in flight per wave (VGPR-backed)
    float v0[8], v1[8];
    const float* p = ll + (size_t)(s0 + wave * 2) * N_CHILD + c0 + lane;
#pragma unroll
    for (int it = 0; it < 8; ++it) {
        v0[it] = p[0];
        v1[it] = p[N_CHILD];
        p += 32 * (size_t)N_CHILD;
    }
#pragma unroll
    for (int it = 0; it < 8; ++it) {
        int sh = it * 16 + wave;          // sample-pair 0..127
        unsigned int packed = (unsigned int)__builtin_amdgcn_cvt_pk_fp8_f32(
            __expf(v0[it]), __expf(v1[it]), 0, false);
        tile[lane * 130 + sh] = (unsigned short)packed;   // 2-way bank alias: free
    }
    __syncthreads();
    unsigned char* dst = ET + (size_t)(z * N_CHILD + c0) * S + s0;
#pragma unroll
    for (int it = 0; it < 4; ++it) {
        int c = it * 16 + wave;
        unsigned int v = *(const unsigned int*)&tile[c * 130 + lane * 2];
        *(unsigned int*)(dst + (size_t)c * S + lane * 4) = v;   // 256 B/wave contiguous
    }
}

// ---- main: out[s,i] = log(sum_k ET[col_k,s]*ew_k) - log(sum_k ew_k) --------

static __device__ inline void fma16(uint4 x, float w, float* a) {
#pragma unroll
    for (int q = 0; q < 4; ++q) {
        unsigned int word = (q == 0) ? x.x : (q == 1) ? x.y : (q == 2) ? x.z : x.w;
        f32x2 lo = __builtin_amdgcn_cvt_pk_f32_fp8(word, false);
        f32x2 hi = __builtin_amdgcn_cvt_pk_f32_fp8(word, true);
        a[q * 4 + 0] = fmaf(lo.x, w, a[q * 4 + 0]);
        a[q * 4 + 1] = fmaf(lo.y, w, a[q * 4 + 1]);
        a[q * 4 + 2] = fmaf(hi.x, w, a[q * 4 + 2]);
        a[q * 4 + 3] = fmaf(hi.y, w, a[q * 4 + 3]);
    }
}

__global__ __launch_bounds__(256, 8) void main_kernel(
        const unsigned char* __restrict__ ET, const int2* __restrict__ ent,
        const int* __restrict__ counts, float* __restrict__ out) {
    __shared__ float lds[TN * LP];    // [node][sample] 16512 B
    int t = threadIdx.x, wave = t >> 6, lane = t & 63;
    int hs = lane >> 5, sl = lane & 31;   // half-wave: hs=0 even entries, hs=1 odd
    int slice = blockIdx.x & 7;           // XCD pin: 4 MB fp8 ET slice per XCD L2
    int nb = blockIdx.x >> 3;
    int i0 = nb * TN;
    const unsigned char* ETs = ET + slice * TSM + sl * 16;   // lane covers 16 samples
    for (int jj = 0; jj < 2; ++jj) {
        int j = wave * 2 + jj;            // each wave owns 2 nodes
        int i = i0 + j;
        int cnt = __builtin_amdgcn_readfirstlane(counts[i]);
        if (cnt > CAP) cnt = CAP;
        const int2* eb = ent + i * CAP;
        float a[16];
#pragma unroll
        for (int u = 0; u < 16; ++u) a[u] = 0.f;
        float z = 0.f;
        int n = (cnt + 1 - hs) >> 1;      // entries for this half: hs, hs+2, ...
        int t2 = 0;
        for (; t2 + 1 < n; t2 += 2) {     // 2 x 16B loads in flight per lane
            int2 e0 = eb[hs + 2 * t2];
            int2 e1 = eb[hs + 2 * t2 + 2];
            uint4 x0 = *(const uint4*)(ETs + (size_t)e0.x * S);
            uint4 x1 = *(const uint4*)(ETs + (size_t)e1.x * S);
            float w0 = __uint_as_float(e0.y);
            float w1 = __uint_as_float(e1.y);
            fma16(x0, w0, a);
            fma16(x1, w1, a);
            z += w0 + w1;
        }
        if (t2 < n) {
            int2 e0 = eb[hs + 2 * t2];
            uint4 x0 = *(const uint4*)(ETs + (size_t)e0.x * S);
            float w0 = __uint_as_float(e0.y);
            fma16(x0, w0, a);
            z += w0;
        }
        // cross-half reduction: lanes l and l^32 hold partials of same outputs
#pragma unroll
        for (int u = 0; u < 16; ++u) a[u] += __shfl_xor(a[u], 32);
        z += __shfl_xor(z, 32);
        float lz = __logf(z);
        // halves split the log work: hs=0 stores u=0..7, hs=1 stores u=8..15
        float r[8];
#pragma unroll
        for (int u = 0; u < 8; ++u) r[u] = __logf(a[hs * 8 + u]) - lz;
        float* dstl = &lds[j * LP + sl * 16 + hs * 8];
        *(float4*)(dstl)     = make_float4(r[0], r[1], r[2], r[3]);
        *(float4*)(dstl + 4) = make_float4(r[4], r[5], r[6], r[7]);
    }
    __syncthreads();
    // out write: 512 samples x 8 nodes, float2/lane -> 512 B contiguous per wave
    float* obase = out + (size_t)slice * TSM * N_NODES + i0;
#pragma unroll
    for (int q = 0; q < 8; ++q) {
        int elem = (t + 256 * q) * 2;     // 0..4094, even
        int s_l = elem >> 3;
        int i_l = elem & 7;               // 0,2,4,6
        float2 v;
        v.x = lds[i_l * LP + s_l];
        v.y = lds[(i_l + 1) * LP + s_l];
        *(float2*)&obase[(size_t)s_l * N_NODES + i_l] = v;
    }
}

// ---- launch ---------------------------------------------------------------

extern "C" void kernel_launch(void* const* d_in, const int* in_sizes, int n_in,
                              void* d_out, int out_size, void* d_ws, size_t ws_size,
                              hipStream_t stream) {
    const float* ll0 = (const float*)d_in[0];
    const float* ll1 = (const float*)d_in[1];
    const float* w0d = (const float*)d_in[2];
    const float* w1d = (const float*)d_in[3];
    const int*   w0r = (const int*)d_in[4];
    const int*   w0c = (const int*)d_in[5];
    const int*   w1r = (const int*)d_in[6];
    const int*   w1c = (const int*)d_in[7];
    float* out = (float*)d_out;

    unsigned char* ET = (unsigned char*)d_ws;                    // 32 MiB
    int2* ent   = (int2*)(ET + (size_t)2 * N_CHILD * S);         // 2048*96*8 B
    int*  counts = (int*)(ent + (size_t)N_NODES * CAP);          // 2048

    hipMemsetAsync(counts, 0, sizeof(int) * N_NODES, stream);
    prep_kernel<<<2112, 1024, 0, stream>>>(ll0, ll1, w0d, w1d, w0r, w0c, w1r, w1c,
                                           ET, ent, counts);
    main_kernel<<<(N_NODES / TN) * (S / TSM), 256, 0, stream>>>(ET, ent, counts, out);
}